// Round 15
// baseline (260.194 us; speedup 1.0000x reference)
//
#include <hip/hip_runtime.h>
#include <math.h>

// ---------------------------------------------------------------------------
// GATv2 3-layer stack on MI355X (gfx950).
// N=50000, E=800000, F=128, H=4, C=32, HC=128.
// CSR: fixed-capacity 128-node buckets (bin -> place, padded-to-4 rows).
// Per layer: gemm_mfma (bf16 MFMA, LDS-free; layer0 reads f32 x directly;
// Bt column-permuted -> packed 8B stores) + fused aggregate (round-8
// structure; STREAMING flows marked non-temporal so XL keeps the XCD-L2).
// NT builtins require ext_vector_type pointers (not HIP_vector_type) -> u32x4.
// NOTE: bf16 row = 128 ch = 16 xubf16-quads -> row stride in u32x4 units is 16.
// ---------------------------------------------------------------------------

#define DPP_QP_XOR1 0xB1
#define DPP_QP_XOR2 0x4E
#define DPP_ROW_MIRROR 0x140
#define DPP_ROW_HALF_MIRROR 0x141

#define EPB 8192
#define MAXB 512
#define ECAP 4096
#define SCAP 4096

template <int CTRL>
__device__ __forceinline__ float dpp_add(float v) {
    int x = __builtin_amdgcn_update_dpp(0, __float_as_int(v), CTRL, 0xf, 0xf, true);
    return v + __int_as_float(x);
}

__device__ __forceinline__ unsigned bf16s(float f) {
    unsigned u = __float_as_uint(f);
    return (u + 0x7fffu + ((u >> 16) & 1u)) >> 16;
}

typedef __bf16 bf16x8 __attribute__((ext_vector_type(8)));
typedef float f32x4 __attribute__((ext_vector_type(4)));
typedef float f32x2 __attribute__((ext_vector_type(2)));
typedef unsigned int u32x4 __attribute__((ext_vector_type(4)));

// ---------------- A: bin edges into 128-node buckets (fixed cap) ----------------

__global__ __launch_bounds__(256) void bin_kernel(
    const int* __restrict__ src, const int* __restrict__ dst,
    int* __restrict__ bucket_count, unsigned* __restrict__ ebuf,
    int E, int NB)
{
    __shared__ int hist[MAXB], lbase[MAXB], gbase[MAXB], cur[MAXB];
    __shared__ int sscan[256];
    __shared__ unsigned stage[EPB];
    const int t = threadIdx.x;
    const int base = blockIdx.x * EPB;
    const int cnt = min(EPB, E - base);

    for (int b = t; b < MAXB; b += 256) hist[b] = 0;
    __syncthreads();
    for (int idx = t; idx < cnt; idx += 256)
        atomicAdd(&hist[dst[base + idx] >> 7], 1);
    __syncthreads();
    {   // exclusive scan of hist[0..511]
        const int a = hist[2 * t], b = hist[2 * t + 1];
        sscan[t] = a + b;
        __syncthreads();
        for (int off = 1; off < 256; off <<= 1) {
            int u = (t >= off) ? sscan[t - off] : 0;
            __syncthreads();
            sscan[t] += u;
            __syncthreads();
        }
        const int ex = sscan[t] - (a + b);
        lbase[2 * t] = ex;
        lbase[2 * t + 1] = ex + a;
    }
    __syncthreads();
    for (int b = t; b < NB; b += 256) {
        const int c = hist[b];
        gbase[b] = (c > 0) ? atomicAdd(&bucket_count[b], c) : 0;
        cur[b] = lbase[b];
    }
    __syncthreads();
    for (int idx = t; idx < cnt; idx += 256) {
        const int d = dst[base + idx];
        const int bk = d >> 7;
        const int lp = atomicAdd(&cur[bk], 1);
        stage[lp] = (unsigned)src[base + idx] | ((unsigned)(d & 127) << 16)
                  | ((unsigned)bk << 23);
    }
    __syncthreads();
    for (int idx = t; idx < cnt; idx += 256) {
        const unsigned v = stage[idx];
        const int bk = v >> 23;
        ebuf[(size_t)bk * ECAP + gbase[bk] + (idx - lbase[bk])] = v;
    }
}

// ---------------- B: per-bucket placement + row_start/deg (padded to 4) ----------

__global__ __launch_bounds__(256) void place_kernel(
    const unsigned* __restrict__ ebuf, const int* __restrict__ bucket_count,
    int* __restrict__ row_start, int* __restrict__ deg,
    unsigned short* __restrict__ src_sorted, int Nn, int NB)
{
    __shared__ int hist[128], lexcl[128], cur[128], s[128];
    __shared__ int ptotS;
    __shared__ unsigned short stage[SCAP];
    const int b = blockIdx.x;
    const int t = threadIdx.x;
    const int node0 = b * 128;
    const int cnt = min(bucket_count[b], ECAP);
    const unsigned* eb = ebuf + (size_t)b * ECAP;

    if (t < 128) hist[t] = 0;
    __syncthreads();
    for (int i = t; i < cnt; i += 256)
        atomicAdd(&hist[(eb[i] >> 16) & 127], 1);
    __syncthreads();
    int pv = 0;
    if (t < 128) { pv = (hist[t] + 3) & ~3; s[t] = pv; }
    __syncthreads();
    for (int off = 1; off < 128; off <<= 1) {
        int u = (t >= off && t < 128) ? s[t - off] : 0;
        __syncthreads();
        if (t < 128) s[t] += u;
        __syncthreads();
    }
    if (t < 128) {
        lexcl[t] = s[t] - pv;
        cur[t] = s[t] - pv;
        const int n = node0 + t;
        if (n < Nn) {
            row_start[n] = b * SCAP + lexcl[t];
            deg[n] = hist[t];
        }
    }
    if (t == 127) ptotS = s[127];
    __syncthreads();
    const int ptot = ptotS;
    for (int i = t; i < ptot; i += 256) stage[i] = 0;
    __syncthreads();
    for (int i = t; i < cnt; i += 256) {
        const unsigned v = eb[i];
        const int lp = atomicAdd(&cur[(v >> 16) & 127], 1);
        stage[lp] = (unsigned short)(v & 0xffffu);
    }
    __syncthreads();
    for (int i = t; i < ptot; i += 256)
        src_sorted[(size_t)b * SCAP + i] = stage[i];
}

// ---------------- prep: W -> Bt (transposed + col-permuted bf16) ----------------
// Bt slot layout: slot = w*64 + nt*16 + l15 holds REAL column w*64 + l15*4 + nt.

__global__ __launch_bounds__(256) void prep_kernel(
    const float* __restrict__ Wl, const float* __restrict__ Wr,
    unsigned short* __restrict__ Bt, int* __restrict__ bucket_cnt, int btTotal)
{
    const int idx = blockIdx.x * blockDim.x + threadIdx.x;
    if (idx < MAXB) bucket_cnt[idx] = 0;
    if (idx < btTotal) {
        const int k = idx & 127;
        const int slot = (idx >> 7) & 255;
        const int l = idx >> 15;
        const int w = slot >> 6;
        const int r6 = slot & 63;
        const int nt = r6 >> 4;
        const int l15 = r6 & 15;
        const int nreal = w * 64 + l15 * 4 + nt;
        const float v = (nreal < 128) ? Wl[l * 16384 + k * 128 + nreal]
                                      : Wr[l * 16384 + k * 128 + (nreal - 128)];
        Bt[idx] = (unsigned short)bf16s(v);
    }
}

// ---------------- GEMM via MFMA (LDS-free, packed 8B stores) ----------------

template <bool F32A>
__global__ __launch_bounds__(256) void gemm_mfma(
    const void* __restrict__ Xv, const unsigned short* __restrict__ Bt,
    const float* __restrict__ bl, const float* __restrict__ br,
    unsigned short* __restrict__ XLb, unsigned short* __restrict__ XRb, int Nn)
{
    const int t = threadIdx.x;
    const int lane = t & 63;
    const int w = t >> 6;
    const int n0 = w * 64;
    const int l15 = lane & 15;
    const int kg = lane >> 4;
    const int rowBase = blockIdx.x * 32;

    f32x4 acc[2][4] = {};

    int ra[2];
    ra[0] = min(rowBase + l15, Nn - 1);
    ra[1] = min(rowBase + 16 + l15, Nn - 1);

#pragma unroll
    for (int ks = 0; ks < 4; ++ks) {
        const int k0 = ks * 32 + kg * 8;
        bf16x8 a[2];
#pragma unroll
        for (int mt = 0; mt < 2; ++mt) {
            if constexpr (F32A) {
                const float* X = (const float*)Xv;
                const float4 f0 = *reinterpret_cast<const float4*>(X + (size_t)ra[mt] * 128 + k0);
                const float4 f1 = *reinterpret_cast<const float4*>(X + (size_t)ra[mt] * 128 + k0 + 4);
                bf16x8 av;
                av[0] = (__bf16)f0.x; av[1] = (__bf16)f0.y;
                av[2] = (__bf16)f0.z; av[3] = (__bf16)f0.w;
                av[4] = (__bf16)f1.x; av[5] = (__bf16)f1.y;
                av[6] = (__bf16)f1.z; av[7] = (__bf16)f1.w;
                a[mt] = av;
            } else {
                const unsigned short* Xb = (const unsigned short*)Xv;
                a[mt] = *reinterpret_cast<const bf16x8*>(Xb + (size_t)ra[mt] * 128 + k0);
            }
        }
#pragma unroll
        for (int nt = 0; nt < 4; ++nt) {
            const int slot = n0 + nt * 16 + l15;
            const bf16x8 b = *reinterpret_cast<const bf16x8*>(Bt + (size_t)slot * 128 + k0);
            acc[0][nt] = __builtin_amdgcn_mfma_f32_16x16x32_bf16(a[0], b, acc[0][nt], 0, 0, 0);
            acc[1][nt] = __builtin_amdgcn_mfma_f32_16x16x32_bf16(a[1], b, acc[1][nt], 0, 0, 0);
        }
    }

    const bool isXL = (w < 2);
    const int cbase = (isXL ? n0 : n0 - 128) + l15 * 4;
    const float* bias = isXL ? (bl + n0) : (br + (n0 - 128));
    const float4 bv = *reinterpret_cast<const float4*>(bias + l15 * 4);
    unsigned short* outp = isXL ? XLb : XRb;

#pragma unroll
    for (int mt = 0; mt < 2; ++mt) {
#pragma unroll
        for (int r = 0; r < 4; ++r) {
            const int row = rowBase + mt * 16 + kg * 4 + r;
            if (row >= Nn) continue;
            uint2 u;
            u.x = bf16s(acc[mt][0][r] + bv.x) | (bf16s(acc[mt][1][r] + bv.y) << 16);
            u.y = bf16s(acc[mt][2][r] + bv.z) | (bf16s(acc[mt][3][r] + bv.w) << 16);
            *reinterpret_cast<uint2*>(outp + (size_t)row * 128 + cbase) = u;
        }
    }
}

// ---------------- Aggregation (round-8 structure + NT streaming) ----------------

__device__ __forceinline__ void unpack8(const u32x4 q, f32x2* v) {
    v[0] = f32x2{__uint_as_float(q[0] << 16), __uint_as_float(q[0] & 0xffff0000u)};
    v[1] = f32x2{__uint_as_float(q[1] << 16), __uint_as_float(q[1] & 0xffff0000u)};
    v[2] = f32x2{__uint_as_float(q[2] << 16), __uint_as_float(q[2] & 0xffff0000u)};
    v[3] = f32x2{__uint_as_float(q[3] << 16), __uint_as_float(q[3] & 0xffff0000u)};
}

__device__ __forceinline__ void edge_accum(const u32x4 q, const f32x2* xr, const f32x2* av,
                                           const bool dead, float& wsum, f32x2* acc) {
    f32x2 xl[4];
    unpack8(q, xl);
    f32x2 pd = {0.f, 0.f};
#pragma unroll
    for (int j = 0; j < 4; ++j) {
        f32x2 tt = xl[j] + xr[j];                         // v_pk_add_f32
        tt = __builtin_elementwise_max(tt, tt * 0.2f);    // pk_mul + max
        pd += tt * av[j];                                 // v_pk_fma_f32
    }
    float part = pd.x + pd.y;
    part = dpp_add<DPP_QP_XOR1>(part);
    part = dpp_add<DPP_QP_XOR2>(part);
    if (dead) part = -INFINITY;
    const float e = __expf(part);
    wsum += e;
    const f32x2 e2 = {e, e};
#pragma unroll
    for (int j = 0; j < 4; ++j) acc[j] += e2 * xl[j];     // v_pk_fma_f32
}

// MODE 0: concat -> outb bf16.  MODE 1: concat + bf16 residual -> outb bf16.
// MODE 2: head-mean -> out f32 (final).
template <int MODE>
__global__ __launch_bounds__(256) void aggregate_kernel(
    const unsigned* __restrict__ XLb, const unsigned* __restrict__ XRb,
    const int* __restrict__ row_start, const int* __restrict__ deg,
    const unsigned short* __restrict__ src_sorted,
    const float* __restrict__ att, const float* __restrict__ obias,
    const float* __restrict__ lng, const float* __restrict__ lnb,
    const unsigned* __restrict__ residb, float* __restrict__ out,
    unsigned* __restrict__ outb, int Nn)
{
    const int lane = threadIdx.x & 63;
    const int wid = threadIdx.x >> 6;
    const int node = blockIdx.x * 4 + wid;
    if (node >= Nn) return;
    const int g = lane >> 4;
    const int i = lane & 15;
    const int c0 = i * 8;

    f32x2 xr[4], av[4];
    {
        // XR is read-once per dispatch: non-temporal (don't evict XL from L2)
        const u32x4 qr = __builtin_nontemporal_load(
            reinterpret_cast<const u32x4*>(XRb) + (size_t)node * 16 + i);
        unpack8(qr, xr);
        const float4 c = *reinterpret_cast<const float4*>(att + c0);
        const float4 d = *reinterpret_cast<const float4*>(att + c0 + 4);
        av[0] = f32x2{c.x, c.y}; av[1] = f32x2{c.z, c.w};
        av[2] = f32x2{d.x, d.y}; av[3] = f32x2{d.z, d.w};
    }

    f32x2 acc[4] = {};
    float wsum = 0.f;

    const int p0 = row_start[node];
    const int dg = deg[node];
    const int p1 = p0 + dg;
    const u32x4* XL4 = reinterpret_cast<const u32x4*>(XLb);

    if (dg > 0) {
        // rows padded to mult of 4 with src 0; index loads clamped to list end.
        // src_sorted is read-once: non-temporal.
        int sA = __builtin_nontemporal_load(src_sorted + min(p0 + g, p1 - 1));
        int sB = __builtin_nontemporal_load(src_sorted + min(p0 + 4 + g, p1 - 1));
        for (int p = p0; p < p1; p += 8) {
            const int sAn = __builtin_nontemporal_load(src_sorted + min(p + 8 + g, p1 - 1));
            const int sBn = __builtin_nontemporal_load(src_sorted + min(p + 12 + g, p1 - 1));
            const u32x4 qA = XL4[(size_t)sA * 16 + i];   // hot gather: keep cached
            edge_accum(qA, xr, av, p + g >= p1, wsum, acc);
            if (p + 4 < p1) {
                const u32x4 qB = XL4[(size_t)sB * 16 + i];
                edge_accum(qB, xr, av, p + 4 + g >= p1, wsum, acc);
            }
            sA = sAn;
            sB = sBn;
        }
    }

    wsum += __shfl_xor(wsum, 16); wsum += __shfl_xor(wsum, 32);
    float o[8];
#pragma unroll
    for (int j = 0; j < 4; ++j) { o[2 * j] = acc[j].x; o[2 * j + 1] = acc[j].y; }
#pragma unroll
    for (int j = 0; j < 8; ++j) {
        o[j] += __shfl_xor(o[j], 16);
        o[j] += __shfl_xor(o[j], 32);
    }

    const float inv = 1.f / (wsum + 1e-16f);
#pragma unroll
    for (int j = 0; j < 8; ++j) o[j] *= inv;

    if (MODE < 2) {
        float v[8], d[8];
        float s = 0.f;
#pragma unroll
        for (int j = 0; j < 8; ++j) { v[j] = o[j] + obias[c0 + j]; s += v[j]; }
        s = dpp_add<DPP_QP_XOR1>(s); s = dpp_add<DPP_QP_XOR2>(s);
        s = dpp_add<DPP_ROW_MIRROR>(s); s = dpp_add<DPP_ROW_HALF_MIRROR>(s);
        const float mu = s * (1.f / 128.f);
        float q = 0.f;
#pragma unroll
        for (int j = 0; j < 8; ++j) { d[j] = v[j] - mu; q = fmaf(d[j], d[j], q); }
        q = dpp_add<DPP_QP_XOR1>(q); q = dpp_add<DPP_QP_XOR2>(q);
        q = dpp_add<DPP_ROW_MIRROR>(q); q = dpp_add<DPP_ROW_HALF_MIRROR>(q);
        const float rstd = rsqrtf(q * (1.f / 128.f) + 1e-5f);
        float h[8];
#pragma unroll
        for (int j = 0; j < 8; ++j)
            h[j] = fmaxf(d[j] * rstd * lng[c0 + j] + lnb[c0 + j], 0.f);
        if (MODE == 1) {
            const u32x4 qr2 = __builtin_nontemporal_load(
                reinterpret_cast<const u32x4*>(residb) + (size_t)node * 16 + i);
            f32x2 rr[4];
            unpack8(qr2, rr);
            h[0] += rr[0].x; h[1] += rr[0].y; h[2] += rr[1].x; h[3] += rr[1].y;
            h[4] += rr[2].x; h[5] += rr[2].y; h[6] += rr[3].x; h[7] += rr[3].y;
        }
        if (g == 0) {
            u32x4 pb;
            pb[0] = bf16s(h[0]) | (bf16s(h[1]) << 16);
            pb[1] = bf16s(h[2]) | (bf16s(h[3]) << 16);
            pb[2] = bf16s(h[4]) | (bf16s(h[5]) << 16);
            pb[3] = bf16s(h[6]) | (bf16s(h[7]) << 16);
            __builtin_nontemporal_store(pb,
                reinterpret_cast<u32x4*>(outb) + (size_t)node * 16 + i);
        }
    } else {
#pragma unroll
        for (int j = 0; j < 8; ++j) {
            o[j] += __shfl_xor(o[j], 4);
            o[j] += __shfl_xor(o[j], 8);
            o[j] *= 0.25f;
        }
        const int cb = (i & 3) * 8;
        float v[8], d[8];
        float s = 0.f;
#pragma unroll
        for (int j = 0; j < 8; ++j) { v[j] = o[j] + obias[cb + j]; s += v[j]; }
        s = dpp_add<DPP_QP_XOR1>(s); s = dpp_add<DPP_QP_XOR2>(s);
        const float mu = s * (1.f / 32.f);
        float q = 0.f;
#pragma unroll
        for (int j = 0; j < 8; ++j) { d[j] = v[j] - mu; q = fmaf(d[j], d[j], q); }
        q = dpp_add<DPP_QP_XOR1>(q); q = dpp_add<DPP_QP_XOR2>(q);
        const float rstd = rsqrtf(q * (1.f / 32.f) + 1e-5f);
        float h[8];
#pragma unroll
        for (int j = 0; j < 8; ++j)
            h[j] = fmaxf(d[j] * rstd * lng[cb + j] + lnb[cb + j], 0.f);
        if (lane < 4) {
            f32x4 s0 = {h[0], h[1], h[2], h[3]};
            f32x4 s1 = {h[4], h[5], h[6], h[7]};
            __builtin_nontemporal_store(s0,
                reinterpret_cast<f32x4*>(out + (size_t)node * 32 + cb));
            __builtin_nontemporal_store(s1,
                reinterpret_cast<f32x4*>(out + (size_t)node * 32 + cb + 4));
        }
    }
}

extern "C" void kernel_launch(void* const* d_in, const int* in_sizes, int n_in,
                              void* d_out, int out_size, void* d_ws, size_t ws_size,
                              hipStream_t stream)
{
    const float* x    = (const float*)d_in[0];
    const int*   ei   = (const int*)d_in[1];
    const float* Wl   = (const float*)d_in[2];
    const float* bl   = (const float*)d_in[3];
    const float* Wr   = (const float*)d_in[4];
    const float* br   = (const float*)d_in[5];
    const float* att  = (const float*)d_in[6];
    const float* ob01 = (const float*)d_in[7];
    const float* ob2  = (const float*)d_in[8];
    const float* lg01 = (const float*)d_in[9];
    const float* lb01 = (const float*)d_in[10];
    const float* lg2  = (const float*)d_in[11];
    const float* lb2  = (const float*)d_in[12];
    float* outp = (float*)d_out;

    const int Nn = in_sizes[0] / 128;
    const int E  = in_sizes[1] / 2;
    const int* srcI = ei;
    const int* dstI = ei + E;
    const int NB = (Nn + 127) / 128;

    char* ws = (char*)d_ws;
    size_t off = 0;
    auto alloc = [&](size_t bytes) {
        void* p = ws + off;
        off += (bytes + 255) & ~(size_t)255;
        return p;
    };
    unsigned short* XLb   = (unsigned short*)alloc((size_t)Nn * 128 * 2);
    unsigned short* XRb   = (unsigned short*)alloc((size_t)Nn * 128 * 2);
    unsigned short* bufAb = (unsigned short*)alloc((size_t)Nn * 128 * 2);
    unsigned short* bufBb = (unsigned short*)alloc((size_t)Nn * 128 * 2);
    unsigned short* Bt    = (unsigned short*)alloc((size_t)3 * 256 * 128 * 2);
    int*   row_start      = (int*)alloc((size_t)Nn * 4);
    int*   deg            = (int*)alloc((size_t)Nn * 4);
    unsigned short* src_sorted = (unsigned short*)alloc((size_t)NB * SCAP * 2 + 256);
    unsigned* ebuf        = (unsigned*)alloc((size_t)NB * ECAP * 4);
    int*   bucket_cnt     = (int*)alloc((size_t)MAXB * 4);
    (void)ws_size;

    const int btTotal = 3 * 256 * 128;

    prep_kernel<<<(btTotal + 255) / 256, 256, 0, stream>>>(Wl, Wr, Bt, bucket_cnt, btTotal);
    bin_kernel<<<(E + EPB - 1) / EPB, 256, 0, stream>>>(srcI, dstI, bucket_cnt, ebuf, E, NB);
    place_kernel<<<NB, 256, 0, stream>>>(ebuf, bucket_cnt, row_start, deg, src_sorted, Nn, NB);

    const int gemm_grid = (Nn + 31) / 32;
    const int agg_grid  = (Nn + 3) / 4;

    // layer 0 (A = f32 x, converted in-register)
    gemm_mfma<true><<<gemm_grid, 256, 0, stream>>>(x, Bt, bl, br, XLb, XRb, Nn);
    aggregate_kernel<0><<<agg_grid, 256, 0, stream>>>((const unsigned*)XLb, (const unsigned*)XRb,
        row_start, deg, src_sorted, att, ob01, lg01, lb01, nullptr, nullptr,
        (unsigned*)bufAb, Nn);

    // layer 1 (residual = bufAb, bf16)
    gemm_mfma<false><<<gemm_grid, 256, 0, stream>>>(bufAb, Bt + 32768, bl + 128, br + 128,
                                                    XLb, XRb, Nn);
    aggregate_kernel<1><<<agg_grid, 256, 0, stream>>>((const unsigned*)XLb, (const unsigned*)XRb,
        row_start, deg, src_sorted, att + 128, ob01 + 128, lg01 + 128, lb01 + 128,
        (const unsigned*)bufAb, nullptr, (unsigned*)bufBb, Nn);

    // layer 2
    gemm_mfma<false><<<gemm_grid, 256, 0, stream>>>(bufBb, Bt + 65536, bl + 256, br + 256,
                                                    XLb, XRb, Nn);
    aggregate_kernel<2><<<agg_grid, 256, 0, stream>>>((const unsigned*)XLb, (const unsigned*)XRb,
        row_start, deg, src_sorted, att + 256, ob2, lg2, lb2, nullptr, outp, nullptr, Nn);
}

// Round 16
// 246.692 us; speedup vs baseline: 1.0547x; 1.0547x over previous
//
#include <hip/hip_runtime.h>
#include <math.h>

// ---------------------------------------------------------------------------
// GATv2 3-layer stack on MI355X (gfx950).
// N=50000, E=800000, F=128, H=4, C=32, HC=128.
// CSR: fixed-capacity 128-node buckets (bin -> place, padded-to-4 rows).
// Per layer: gemm_mfma (bf16 MFMA, LDS-free; layer0 reads f32 x directly;
// Bt column-permuted -> packed 8B stores) + fused aggregate (round-8
// structure: 8 edges/iter, index prefetch, clamped loads; f32x2 packed
// VALU, DPP reductions, LN/ReLU). All hot-path loads CACHED (round-15
// lesson: NT on reused streams regresses). NT only on the final output.
// NOTE: bf16 row = 128 ch = 16 u32x4 -> row stride in u32x4 units is 16.
// ---------------------------------------------------------------------------

#define DPP_QP_XOR1 0xB1
#define DPP_QP_XOR2 0x4E
#define DPP_ROW_MIRROR 0x140
#define DPP_ROW_HALF_MIRROR 0x141

#define EPB 8192
#define MAXB 512
#define ECAP 4096
#define SCAP 4096

template <int CTRL>
__device__ __forceinline__ float dpp_add(float v) {
    int x = __builtin_amdgcn_update_dpp(0, __float_as_int(v), CTRL, 0xf, 0xf, true);
    return v + __int_as_float(x);
}

__device__ __forceinline__ unsigned bf16s(float f) {
    unsigned u = __float_as_uint(f);
    return (u + 0x7fffu + ((u >> 16) & 1u)) >> 16;
}

typedef __bf16 bf16x8 __attribute__((ext_vector_type(8)));
typedef float f32x4 __attribute__((ext_vector_type(4)));
typedef float f32x2 __attribute__((ext_vector_type(2)));

// ---------------- A: bin edges into 128-node buckets (fixed cap) ----------------

__global__ __launch_bounds__(256) void bin_kernel(
    const int* __restrict__ src, const int* __restrict__ dst,
    int* __restrict__ bucket_count, unsigned* __restrict__ ebuf,
    int E, int NB)
{
    __shared__ int hist[MAXB], lbase[MAXB], gbase[MAXB], cur[MAXB];
    __shared__ int sscan[256];
    __shared__ unsigned stage[EPB];
    const int t = threadIdx.x;
    const int base = blockIdx.x * EPB;
    const int cnt = min(EPB, E - base);

    for (int b = t; b < MAXB; b += 256) hist[b] = 0;
    __syncthreads();
    for (int idx = t; idx < cnt; idx += 256)
        atomicAdd(&hist[dst[base + idx] >> 7], 1);
    __syncthreads();
    {   // exclusive scan of hist[0..511]
        const int a = hist[2 * t], b = hist[2 * t + 1];
        sscan[t] = a + b;
        __syncthreads();
        for (int off = 1; off < 256; off <<= 1) {
            int u = (t >= off) ? sscan[t - off] : 0;
            __syncthreads();
            sscan[t] += u;
            __syncthreads();
        }
        const int ex = sscan[t] - (a + b);
        lbase[2 * t] = ex;
        lbase[2 * t + 1] = ex + a;
    }
    __syncthreads();
    for (int b = t; b < NB; b += 256) {
        const int c = hist[b];
        gbase[b] = (c > 0) ? atomicAdd(&bucket_count[b], c) : 0;
        cur[b] = lbase[b];
    }
    __syncthreads();
    for (int idx = t; idx < cnt; idx += 256) {
        const int d = dst[base + idx];
        const int bk = d >> 7;
        const int lp = atomicAdd(&cur[bk], 1);
        stage[lp] = (unsigned)src[base + idx] | ((unsigned)(d & 127) << 16)
                  | ((unsigned)bk << 23);
    }
    __syncthreads();
    for (int idx = t; idx < cnt; idx += 256) {
        const unsigned v = stage[idx];
        const int bk = v >> 23;
        ebuf[(size_t)bk * ECAP + gbase[bk] + (idx - lbase[bk])] = v;
    }
}

// ---------------- B: per-bucket placement + row_start/deg (padded to 4) ----------

__global__ __launch_bounds__(256) void place_kernel(
    const unsigned* __restrict__ ebuf, const int* __restrict__ bucket_count,
    int* __restrict__ row_start, int* __restrict__ deg,
    unsigned short* __restrict__ src_sorted, int Nn, int NB)
{
    __shared__ int hist[128], lexcl[128], cur[128], s[128];
    __shared__ int ptotS;
    __shared__ unsigned short stage[SCAP];
    const int b = blockIdx.x;
    const int t = threadIdx.x;
    const int node0 = b * 128;
    const int cnt = min(bucket_count[b], ECAP);
    const unsigned* eb = ebuf + (size_t)b * ECAP;

    if (t < 128) hist[t] = 0;
    __syncthreads();
    for (int i = t; i < cnt; i += 256)
        atomicAdd(&hist[(eb[i] >> 16) & 127], 1);
    __syncthreads();
    int pv = 0;
    if (t < 128) { pv = (hist[t] + 3) & ~3; s[t] = pv; }
    __syncthreads();
    for (int off = 1; off < 128; off <<= 1) {
        int u = (t >= off && t < 128) ? s[t - off] : 0;
        __syncthreads();
        if (t < 128) s[t] += u;
        __syncthreads();
    }
    if (t < 128) {
        lexcl[t] = s[t] - pv;
        cur[t] = s[t] - pv;
        const int n = node0 + t;
        if (n < Nn) {
            row_start[n] = b * SCAP + lexcl[t];
            deg[n] = hist[t];
        }
    }
    if (t == 127) ptotS = s[127];
    __syncthreads();
    const int ptot = ptotS;
    for (int i = t; i < ptot; i += 256) stage[i] = 0;
    __syncthreads();
    for (int i = t; i < cnt; i += 256) {
        const unsigned v = eb[i];
        const int lp = atomicAdd(&cur[(v >> 16) & 127], 1);
        stage[lp] = (unsigned short)(v & 0xffffu);
    }
    __syncthreads();
    for (int i = t; i < ptot; i += 256)
        src_sorted[(size_t)b * SCAP + i] = stage[i];
}

// ---------------- prep: W -> Bt (transposed + col-permuted bf16) ----------------
// Bt slot layout: slot = w*64 + nt*16 + l15 holds REAL column w*64 + l15*4 + nt.

__global__ __launch_bounds__(256) void prep_kernel(
    const float* __restrict__ Wl, const float* __restrict__ Wr,
    unsigned short* __restrict__ Bt, int* __restrict__ bucket_cnt, int btTotal)
{
    const int idx = blockIdx.x * blockDim.x + threadIdx.x;
    if (idx < MAXB) bucket_cnt[idx] = 0;
    if (idx < btTotal) {
        const int k = idx & 127;
        const int slot = (idx >> 7) & 255;
        const int l = idx >> 15;
        const int w = slot >> 6;
        const int r6 = slot & 63;
        const int nt = r6 >> 4;
        const int l15 = r6 & 15;
        const int nreal = w * 64 + l15 * 4 + nt;
        const float v = (nreal < 128) ? Wl[l * 16384 + k * 128 + nreal]
                                      : Wr[l * 16384 + k * 128 + (nreal - 128)];
        Bt[idx] = (unsigned short)bf16s(v);
    }
}

// ---------------- GEMM via MFMA (LDS-free, packed 8B stores) ----------------

template <bool F32A>
__global__ __launch_bounds__(256) void gemm_mfma(
    const void* __restrict__ Xv, const unsigned short* __restrict__ Bt,
    const float* __restrict__ bl, const float* __restrict__ br,
    unsigned short* __restrict__ XLb, unsigned short* __restrict__ XRb, int Nn)
{
    const int t = threadIdx.x;
    const int lane = t & 63;
    const int w = t >> 6;
    const int n0 = w * 64;
    const int l15 = lane & 15;
    const int kg = lane >> 4;
    const int rowBase = blockIdx.x * 32;

    f32x4 acc[2][4] = {};

    int ra[2];
    ra[0] = min(rowBase + l15, Nn - 1);
    ra[1] = min(rowBase + 16 + l15, Nn - 1);

#pragma unroll
    for (int ks = 0; ks < 4; ++ks) {
        const int k0 = ks * 32 + kg * 8;
        bf16x8 a[2];
#pragma unroll
        for (int mt = 0; mt < 2; ++mt) {
            if constexpr (F32A) {
                const float* X = (const float*)Xv;
                const float4 f0 = *reinterpret_cast<const float4*>(X + (size_t)ra[mt] * 128 + k0);
                const float4 f1 = *reinterpret_cast<const float4*>(X + (size_t)ra[mt] * 128 + k0 + 4);
                bf16x8 av;
                av[0] = (__bf16)f0.x; av[1] = (__bf16)f0.y;
                av[2] = (__bf16)f0.z; av[3] = (__bf16)f0.w;
                av[4] = (__bf16)f1.x; av[5] = (__bf16)f1.y;
                av[6] = (__bf16)f1.z; av[7] = (__bf16)f1.w;
                a[mt] = av;
            } else {
                const unsigned short* Xb = (const unsigned short*)Xv;
                a[mt] = *reinterpret_cast<const bf16x8*>(Xb + (size_t)ra[mt] * 128 + k0);
            }
        }
#pragma unroll
        for (int nt = 0; nt < 4; ++nt) {
            const int slot = n0 + nt * 16 + l15;
            const bf16x8 b = *reinterpret_cast<const bf16x8*>(Bt + (size_t)slot * 128 + k0);
            acc[0][nt] = __builtin_amdgcn_mfma_f32_16x16x32_bf16(a[0], b, acc[0][nt], 0, 0, 0);
            acc[1][nt] = __builtin_amdgcn_mfma_f32_16x16x32_bf16(a[1], b, acc[1][nt], 0, 0, 0);
        }
    }

    const bool isXL = (w < 2);
    const int cbase = (isXL ? n0 : n0 - 128) + l15 * 4;
    const float* bias = isXL ? (bl + n0) : (br + (n0 - 128));
    const float4 bv = *reinterpret_cast<const float4*>(bias + l15 * 4);
    unsigned short* outp = isXL ? XLb : XRb;

#pragma unroll
    for (int mt = 0; mt < 2; ++mt) {
#pragma unroll
        for (int r = 0; r < 4; ++r) {
            const int row = rowBase + mt * 16 + kg * 4 + r;
            if (row >= Nn) continue;
            uint2 u;
            u.x = bf16s(acc[mt][0][r] + bv.x) | (bf16s(acc[mt][1][r] + bv.y) << 16);
            u.y = bf16s(acc[mt][2][r] + bv.z) | (bf16s(acc[mt][3][r] + bv.w) << 16);
            *reinterpret_cast<uint2*>(outp + (size_t)row * 128 + cbase) = u;
        }
    }
}

// ---------------- Aggregation (round-8 structure) ----------------

__device__ __forceinline__ void unpack8(const uint4 q, f32x2* v) {
    v[0] = f32x2{__uint_as_float(q.x << 16), __uint_as_float(q.x & 0xffff0000u)};
    v[1] = f32x2{__uint_as_float(q.y << 16), __uint_as_float(q.y & 0xffff0000u)};
    v[2] = f32x2{__uint_as_float(q.z << 16), __uint_as_float(q.z & 0xffff0000u)};
    v[3] = f32x2{__uint_as_float(q.w << 16), __uint_as_float(q.w & 0xffff0000u)};
}

__device__ __forceinline__ void edge_accum(const uint4 q, const f32x2* xr, const f32x2* av,
                                           const bool dead, float& wsum, f32x2* acc) {
    f32x2 xl[4];
    unpack8(q, xl);
    f32x2 pd = {0.f, 0.f};
#pragma unroll
    for (int j = 0; j < 4; ++j) {
        f32x2 tt = xl[j] + xr[j];                         // v_pk_add_f32
        tt = __builtin_elementwise_max(tt, tt * 0.2f);    // pk_mul + max
        pd += tt * av[j];                                 // v_pk_fma_f32
    }
    float part = pd.x + pd.y;
    part = dpp_add<DPP_QP_XOR1>(part);
    part = dpp_add<DPP_QP_XOR2>(part);
    if (dead) part = -INFINITY;
    const float e = __expf(part);
    wsum += e;
    const f32x2 e2 = {e, e};
#pragma unroll
    for (int j = 0; j < 4; ++j) acc[j] += e2 * xl[j];     // v_pk_fma_f32
}

// MODE 0: concat -> outb bf16.  MODE 1: concat + bf16 residual -> outb bf16.
// MODE 2: head-mean -> out f32 (final, NT stores: never re-read on device).
template <int MODE>
__global__ __launch_bounds__(256) void aggregate_kernel(
    const unsigned* __restrict__ XLb, const unsigned* __restrict__ XRb,
    const int* __restrict__ row_start, const int* __restrict__ deg,
    const unsigned short* __restrict__ src_sorted,
    const float* __restrict__ att, const float* __restrict__ obias,
    const float* __restrict__ lng, const float* __restrict__ lnb,
    const unsigned* __restrict__ residb, float* __restrict__ out,
    unsigned* __restrict__ outb, int Nn)
{
    const int lane = threadIdx.x & 63;
    const int wid = threadIdx.x >> 6;
    const int node = blockIdx.x * 4 + wid;
    if (node >= Nn) return;
    const int g = lane >> 4;
    const int i = lane & 15;
    const int c0 = i * 8;

    f32x2 xr[4], av[4];
    {
        const uint4 qr = reinterpret_cast<const uint4*>(XRb)[(size_t)node * 16 + i];
        unpack8(qr, xr);
        const float4 c = *reinterpret_cast<const float4*>(att + c0);
        const float4 d = *reinterpret_cast<const float4*>(att + c0 + 4);
        av[0] = f32x2{c.x, c.y}; av[1] = f32x2{c.z, c.w};
        av[2] = f32x2{d.x, d.y}; av[3] = f32x2{d.z, d.w};
    }

    f32x2 acc[4] = {};
    float wsum = 0.f;

    const int p0 = row_start[node];
    const int dg = deg[node];
    const int p1 = p0 + dg;
    const uint4* XL4 = reinterpret_cast<const uint4*>(XLb);

    if (dg > 0) {
        // rows padded to mult of 4 with src 0; index loads clamped to list end.
        int sA = src_sorted[min(p0 + g, p1 - 1)];
        int sB = src_sorted[min(p0 + 4 + g, p1 - 1)];
        for (int p = p0; p < p1; p += 8) {
            const int sAn = src_sorted[min(p + 8 + g, p1 - 1)];
            const int sBn = src_sorted[min(p + 12 + g, p1 - 1)];
            const uint4 qA = XL4[(size_t)sA * 16 + i];
            edge_accum(qA, xr, av, p + g >= p1, wsum, acc);
            if (p + 4 < p1) {
                const uint4 qB = XL4[(size_t)sB * 16 + i];
                edge_accum(qB, xr, av, p + 4 + g >= p1, wsum, acc);
            }
            sA = sAn;
            sB = sBn;
        }
    }

    wsum += __shfl_xor(wsum, 16); wsum += __shfl_xor(wsum, 32);
    float o[8];
#pragma unroll
    for (int j = 0; j < 4; ++j) { o[2 * j] = acc[j].x; o[2 * j + 1] = acc[j].y; }
#pragma unroll
    for (int j = 0; j < 8; ++j) {
        o[j] += __shfl_xor(o[j], 16);
        o[j] += __shfl_xor(o[j], 32);
    }

    const float inv = 1.f / (wsum + 1e-16f);
#pragma unroll
    for (int j = 0; j < 8; ++j) o[j] *= inv;

    if (MODE < 2) {
        float v[8], d[8];
        float s = 0.f;
#pragma unroll
        for (int j = 0; j < 8; ++j) { v[j] = o[j] + obias[c0 + j]; s += v[j]; }
        s = dpp_add<DPP_QP_XOR1>(s); s = dpp_add<DPP_QP_XOR2>(s);
        s = dpp_add<DPP_ROW_MIRROR>(s); s = dpp_add<DPP_ROW_HALF_MIRROR>(s);
        const float mu = s * (1.f / 128.f);
        float q = 0.f;
#pragma unroll
        for (int j = 0; j < 8; ++j) { d[j] = v[j] - mu; q = fmaf(d[j], d[j], q); }
        q = dpp_add<DPP_QP_XOR1>(q); q = dpp_add<DPP_QP_XOR2>(q);
        q = dpp_add<DPP_ROW_MIRROR>(q); q = dpp_add<DPP_ROW_HALF_MIRROR>(q);
        const float rstd = rsqrtf(q * (1.f / 128.f) + 1e-5f);
        float h[8];
#pragma unroll
        for (int j = 0; j < 8; ++j)
            h[j] = fmaxf(d[j] * rstd * lng[c0 + j] + lnb[c0 + j], 0.f);
        if (MODE == 1) {
            const uint4 qr2 = reinterpret_cast<const uint4*>(residb)[(size_t)node * 16 + i];
            f32x2 rr[4];
            unpack8(qr2, rr);
            h[0] += rr[0].x; h[1] += rr[0].y; h[2] += rr[1].x; h[3] += rr[1].y;
            h[4] += rr[2].x; h[5] += rr[2].y; h[6] += rr[3].x; h[7] += rr[3].y;
        }
        if (g == 0) {
            uint4 pb;
            pb.x = bf16s(h[0]) | (bf16s(h[1]) << 16);
            pb.y = bf16s(h[2]) | (bf16s(h[3]) << 16);
            pb.z = bf16s(h[4]) | (bf16s(h[5]) << 16);
            pb.w = bf16s(h[6]) | (bf16s(h[7]) << 16);
            reinterpret_cast<uint4*>(outb)[(size_t)node * 16 + i] = pb;
        }
    } else {
#pragma unroll
        for (int j = 0; j < 8; ++j) {
            o[j] += __shfl_xor(o[j], 4);
            o[j] += __shfl_xor(o[j], 8);
            o[j] *= 0.25f;
        }
        const int cb = (i & 3) * 8;
        float v[8], d[8];
        float s = 0.f;
#pragma unroll
        for (int j = 0; j < 8; ++j) { v[j] = o[j] + obias[cb + j]; s += v[j]; }
        s = dpp_add<DPP_QP_XOR1>(s); s = dpp_add<DPP_QP_XOR2>(s);
        const float mu = s * (1.f / 32.f);
        float q = 0.f;
#pragma unroll
        for (int j = 0; j < 8; ++j) { d[j] = v[j] - mu; q = fmaf(d[j], d[j], q); }
        q = dpp_add<DPP_QP_XOR1>(q); q = dpp_add<DPP_QP_XOR2>(q);
        const float rstd = rsqrtf(q * (1.f / 32.f) + 1e-5f);
        float h[8];
#pragma unroll
        for (int j = 0; j < 8; ++j)
            h[j] = fmaxf(d[j] * rstd * lng[cb + j] + lnb[cb + j], 0.f);
        if (lane < 4) {
            f32x4 s0 = {h[0], h[1], h[2], h[3]};
            f32x4 s1 = {h[4], h[5], h[6], h[7]};
            __builtin_nontemporal_store(s0,
                reinterpret_cast<f32x4*>(out + (size_t)node * 32 + cb));
            __builtin_nontemporal_store(s1,
                reinterpret_cast<f32x4*>(out + (size_t)node * 32 + cb + 4));
        }
    }
}

extern "C" void kernel_launch(void* const* d_in, const int* in_sizes, int n_in,
                              void* d_out, int out_size, void* d_ws, size_t ws_size,
                              hipStream_t stream)
{
    const float* x    = (const float*)d_in[0];
    const int*   ei   = (const int*)d_in[1];
    const float* Wl   = (const float*)d_in[2];
    const float* bl   = (const float*)d_in[3];
    const float* Wr   = (const float*)d_in[4];
    const float* br   = (const float*)d_in[5];
    const float* att  = (const float*)d_in[6];
    const float* ob01 = (const float*)d_in[7];
    const float* ob2  = (const float*)d_in[8];
    const float* lg01 = (const float*)d_in[9];
    const float* lb01 = (const float*)d_in[10];
    const float* lg2  = (const float*)d_in[11];
    const float* lb2  = (const float*)d_in[12];
    float* outp = (float*)d_out;

    const int Nn = in_sizes[0] / 128;
    const int E  = in_sizes[1] / 2;
    const int* srcI = ei;
    const int* dstI = ei + E;
    const int NB = (Nn + 127) / 128;

    char* ws = (char*)d_ws;
    size_t off = 0;
    auto alloc = [&](size_t bytes) {
        void* p = ws + off;
        off += (bytes + 255) & ~(size_t)255;
        return p;
    };
    unsigned short* XLb   = (unsigned short*)alloc((size_t)Nn * 128 * 2);
    unsigned short* XRb   = (unsigned short*)alloc((size_t)Nn * 128 * 2);
    unsigned short* bufAb = (unsigned short*)alloc((size_t)Nn * 128 * 2);
    unsigned short* bufBb = (unsigned short*)alloc((size_t)Nn * 128 * 2);
    unsigned short* Bt    = (unsigned short*)alloc((size_t)3 * 256 * 128 * 2);
    int*   row_start      = (int*)alloc((size_t)Nn * 4);
    int*   deg            = (int*)alloc((size_t)Nn * 4);
    unsigned short* src_sorted = (unsigned short*)alloc((size_t)NB * SCAP * 2 + 256);
    unsigned* ebuf        = (unsigned*)alloc((size_t)NB * ECAP * 4);
    int*   bucket_cnt     = (int*)alloc((size_t)MAXB * 4);
    (void)ws_size;

    const int btTotal = 3 * 256 * 128;

    prep_kernel<<<(btTotal + 255) / 256, 256, 0, stream>>>(Wl, Wr, Bt, bucket_cnt, btTotal);
    bin_kernel<<<(E + EPB - 1) / EPB, 256, 0, stream>>>(srcI, dstI, bucket_cnt, ebuf, E, NB);
    place_kernel<<<NB, 256, 0, stream>>>(ebuf, bucket_cnt, row_start, deg, src_sorted, Nn, NB);

    const int gemm_grid = (Nn + 31) / 32;
    const int agg_grid  = (Nn + 3) / 4;

    // layer 0 (A = f32 x, converted in-register)
    gemm_mfma<true><<<gemm_grid, 256, 0, stream>>>(x, Bt, bl, br, XLb, XRb, Nn);
    aggregate_kernel<0><<<agg_grid, 256, 0, stream>>>((const unsigned*)XLb, (const unsigned*)XRb,
        row_start, deg, src_sorted, att, ob01, lg01, lb01, nullptr, nullptr,
        (unsigned*)bufAb, Nn);

    // layer 1 (residual = bufAb, bf16)
    gemm_mfma<false><<<gemm_grid, 256, 0, stream>>>(bufAb, Bt + 32768, bl + 128, br + 128,
                                                    XLb, XRb, Nn);
    aggregate_kernel<1><<<agg_grid, 256, 0, stream>>>((const unsigned*)XLb, (const unsigned*)XRb,
        row_start, deg, src_sorted, att + 128, ob01 + 128, lg01 + 128, lb01 + 128,
        (const unsigned*)bufAb, nullptr, (unsigned*)bufBb, Nn);

    // layer 2
    gemm_mfma<false><<<gemm_grid, 256, 0, stream>>>(bufBb, Bt + 65536, bl + 256, br + 256,
                                                    XLb, XRb, Nn);
    aggregate_kernel<2><<<agg_grid, 256, 0, stream>>>((const unsigned*)XLb, (const unsigned*)XRb,
        row_start, deg, src_sorted, att + 256, ob2, lg2, lb2, nullptr, outp, nullptr, Nn);
}